// Round 1
// baseline (240.736 us; speedup 1.0000x reference)
//
#include <hip/hip_runtime.h>
#include <cstdint>
#include <cstddef>

#define DEV __device__ __forceinline__

typedef __bf16 bf16_t;
typedef __bf16 bf16x8 __attribute__((ext_vector_type(8)));
typedef float  f32x4  __attribute__((ext_vector_type(4)));
typedef unsigned int u32x4 __attribute__((ext_vector_type(4)));

DEV bf16_t f2bf(float x) { return (bf16_t)x; }   // RNE cast

// ---- problem sizes ----
constexpr int R_ = 500, C_ = 512, H_ = 38, W_ = 38, K_ = 20;
constexpr int HID = 4096, FEAT = 4608, MP = 512;  // MP = padded M

// ---- workspace layout ----
constexpr size_t alup(size_t x) { return (x + 255) & ~(size_t)255; }
constexpr size_t O_FMT  = 0;                                        // fmap transposed [38*38][512] f32
constexpr size_t O_RSC  = alup(O_FMT  + (size_t)H_*W_*C_*4);        // rois_sc [500][4] f32
constexpr size_t O_FEAT = alup(O_RSC  + (size_t)R_*4*4);            // feat bf16 [512][4608]
constexpr size_t O_FC6  = alup(O_FEAT + (size_t)MP*FEAT*2);         // fc6 bf16 [512][4096]
constexpr size_t O_FC7  = alup(O_FC6  + (size_t)MP*HID*2);          // fc7 f32 [512][4096]
constexpr size_t O_PC   = alup(O_FC7  + (size_t)MP*HID*4);          // pc [500][20] f32
constexpr size_t O_LD   = alup(O_PC   + (size_t)R_*K_*4);           // logits_d [500][20] f32
constexpr size_t O_AN   = alup(O_LD   + (size_t)R_*K_*4);           // ||fc7[r]||^2 [512] f32
constexpr size_t O_OS   = alup(O_AN   + (size_t)MP*4);              // out_sum [20]
constexpr size_t O_HI   = alup(O_OS   + (size_t)K_*4);              // h_idx [20] int
constexpr size_t O_D    = alup(O_HI   + (size_t)K_*4);              // D [500][20] f32
constexpr size_t O_PART = alup(O_D    + (size_t)R_*K_*4);           // split-K partials
constexpr size_t WS_K4  = O_PART + (size_t)4*MP*HID*4;

// ---- fmap transpose: [C][H][W] -> [H*W][C] for coalesced ROI-pool reads ----
__global__ void __launch_bounds__(256) k_transpose(const float* __restrict__ fmap,
                                                   float* __restrict__ fmapt) {
    int p = blockIdx.x, t = threadIdx.x;                 // p in [0, 1444)
    fmapt[(size_t)p*C_ + t]       = fmap[(size_t)t*(H_*W_) + p];
    fmapt[(size_t)p*C_ + t + 256] = fmap[(size_t)(t+256)*(H_*W_) + p];
}

// ---- ROI max pool: feat[r, c*9 + pr*3 + pc] ----
__global__ void __launch_bounds__(256) k_roipool(const float* __restrict__ fmapt,
                                                 const float* __restrict__ rois,
                                                 bf16_t* __restrict__ feat,
                                                 float* __restrict__ rois_sc) {
    int r = blockIdx.x, t = threadIdx.x;
    if (r >= R_) {   // zero the M-padding rows so the GEMM sees zeros
        for (int i = t; i < FEAT; i += 256) feat[(size_t)r*FEAT + i] = (bf16_t)0.f;
        return;
    }
    int x1 = (int)floorf(rois[r*4+0] * 0.0625f);
    int y1 = (int)floorf(rois[r*4+1] * 0.0625f);
    int x2 = (int)floorf(rois[r*4+2] * 0.0625f);
    int y2 = (int)floorf(rois[r*4+3] * 0.0625f);
    if (t == 0) {
        rois_sc[r*4+0] = (float)x1; rois_sc[r*4+1] = (float)y1;
        rois_sc[r*4+2] = (float)x2; rois_sc[r*4+3] = (float)y2;
    }
    int Lx = x2 - x1, Ly = y2 - y1;
#pragma unroll
    for (int pr = 0; pr < 3; ++pr) {
        int rs = y1 + (pr*Ly)/3, re = y1 + ((pr+1)*Ly + 2)/3;
#pragma unroll
        for (int px = 0; px < 3; ++px) {
            int cs = x1 + (px*Lx)/3, ce = x1 + ((px+1)*Lx + 2)/3;
            float m0 = -3.402823466e38f, m1 = -3.402823466e38f;
            for (int y = rs; y < re; ++y)
                for (int x = cs; x < ce; ++x) {
                    const float* p = fmapt + (size_t)(y*W_ + x)*C_;
                    m0 = fmaxf(m0, p[t]);
                    m1 = fmaxf(m1, p[t + 256]);
                }
            int bin = pr*3 + px;
            feat[(size_t)r*FEAT + (size_t)t*9       + bin] = f2bf(m0);
            feat[(size_t)r*FEAT + (size_t)(t+256)*9 + bin] = f2bf(m1);
        }
    }
}

// ---- bf16 MFMA GEMM: part[s] += A[512xK](bf16) * B[Kx4096](f32, cast to bf16) ----
// BM=BN=128, BK=64, 4 waves (64x64 each), double-buffered LDS, split-K via blockIdx.z
__global__ void __launch_bounds__(256, 2)
k_gemm(const bf16_t* __restrict__ A, const float* __restrict__ B,
       float* __restrict__ part, int KDIM, int nts) {
    __shared__ bf16_t Al[2][128][72];   // 144B row stride: uniform bank spread for b128
    __shared__ bf16_t Bl[2][128][72];   // stored transposed: [n][k]
    const int t = threadIdx.x;
    const int lane = t & 63, wid = t >> 6;
    const int wr = wid >> 1, wc = wid & 1;
    const int brow = blockIdx.y * 128, bcol = blockIdx.x * 128;
    const int kt0 = blockIdx.z * nts;

    f32x4 acc[4][4] = {};
    u32x4 areg[4];
    float breg[4][8];

    auto load_tile = [&](int kt) {
        const int k0 = kt * 64;
#pragma unroll
        for (int i = 0; i < 4; ++i) {          // A: 128 rows x 64 k, 16B per slot
            int slot = t + i*256;
            int row = slot >> 3, kg = slot & 7;
            areg[i] = *reinterpret_cast<const u32x4*>(A + (size_t)(brow + row)*KDIM + k0 + kg*8);
        }
#pragma unroll
        for (int i = 0; i < 4; ++i) {          // B: columnar gather (8 consecutive k per n)
            int slot = t + i*256;
            int n = slot & 127, kg = slot >> 7;
            const float* src = B + (size_t)(k0 + kg*8)*HID + bcol + n;
#pragma unroll
            for (int j = 0; j < 8; ++j) breg[i][j] = src[(size_t)j*HID];
        }
    };
    auto write_tile = [&](int buf) {
#pragma unroll
        for (int i = 0; i < 4; ++i) {
            int slot = t + i*256;
            int row = slot >> 3, kg = slot & 7;
            *reinterpret_cast<u32x4*>(&Al[buf][row][kg*8]) = areg[i];
        }
#pragma unroll
        for (int i = 0; i < 4; ++i) {
            int slot = t + i*256;
            int n = slot & 127, kg = slot >> 7;
            bf16x8 v;
#pragma unroll
            for (int j = 0; j < 8; ++j) v[j] = f2bf(breg[i][j]);
            *reinterpret_cast<bf16x8*>(&Bl[buf][n][kg*8]) = v;
        }
    };

    load_tile(kt0);
    write_tile(0);
    __syncthreads();

    for (int it = 0; it < nts; ++it) {
        const int cur = it & 1;
        if (it + 1 < nts) load_tile(kt0 + it + 1);   // overlap global loads with MFMA
#pragma unroll
        for (int kk = 0; kk < 2; ++kk) {
            bf16x8 af[4], bfr[4];
#pragma unroll
            for (int m = 0; m < 4; ++m)
                af[m] = *reinterpret_cast<const bf16x8*>(
                    &Al[cur][wr*64 + m*16 + (lane & 15)][kk*32 + (lane >> 4)*8]);
#pragma unroll
            for (int n = 0; n < 4; ++n)
                bfr[n] = *reinterpret_cast<const bf16x8*>(
                    &Bl[cur][wc*64 + n*16 + (lane & 15)][kk*32 + (lane >> 4)*8]);
#pragma unroll
            for (int m = 0; m < 4; ++m)
#pragma unroll
                for (int n = 0; n < 4; ++n)
                    acc[m][n] = __builtin_amdgcn_mfma_f32_16x16x32_bf16(af[m], bfr[n], acc[m][n], 0, 0, 0);
        }
        if (it + 1 < nts) { write_tile(cur ^ 1); __syncthreads(); }
    }

    float* dst = part + (size_t)blockIdx.z * MP * HID;
#pragma unroll
    for (int m = 0; m < 4; ++m) {
        int row0 = brow + wr*64 + m*16 + ((lane >> 4) << 2);
#pragma unroll
        for (int n = 0; n < 4; ++n) {
            int col = bcol + wc*64 + n*16 + (lane & 15);
#pragma unroll
            for (int j = 0; j < 4; ++j)
                dst[(size_t)(row0 + j)*HID + col] = acc[m][n][j];
        }
    }
}

// ---- split-K reduce + bias; writes bf16 (fc6) or f32 (fc7) ----
__global__ void __launch_bounds__(256) k_reduce(const float* __restrict__ part,
                                                const float* __restrict__ bias,
                                                bf16_t* __restrict__ ob, float* __restrict__ of,
                                                int ksplit) {
    size_t idx = ((size_t)blockIdx.x*256 + threadIdx.x) * 4;
    f32x4 s = *reinterpret_cast<const f32x4*>(part + idx);
    for (int ss = 1; ss < ksplit; ++ss)
        s += *reinterpret_cast<const f32x4*>(part + (size_t)ss*MP*HID + idx);
    int col = (int)(idx & (HID - 1));
    s += *reinterpret_cast<const f32x4*>(bias + col);
    if (ob) {
#pragma unroll
        for (int j = 0; j < 4; ++j) ob[idx + j] = f2bf(s[j]);
    } else {
        *reinterpret_cast<f32x4*>(of + idx) = s;
    }
}

// ---- heads: logits_c (+softmax -> pc), logits_d (raw), ||fc7[r]||^2 ----
__global__ void __launch_bounds__(256) k_heads(const float* __restrict__ fc7,
        const float* __restrict__ W8c, const float* __restrict__ b8c,
        const float* __restrict__ W8d, const float* __restrict__ b8d,
        float* __restrict__ pc, float* __restrict__ ld_out, float* __restrict__ An) {
    int r = blockIdx.x, t = threadIdx.x;
    float ac[20] = {}, ad[20] = {}, aa = 0.f;
    const float* frow = fc7 + (size_t)r*HID;
    for (int e = 0; e < 16; ++e) {
        int i = e*256 + t;
        float x = frow[i];
        aa = fmaf(x, x, aa);
        const float* wc = W8c + (size_t)i*K_;
        const float* wd = W8d + (size_t)i*K_;
#pragma unroll
        for (int k = 0; k < 20; ++k) {
            ac[k] = fmaf(x, wc[k], ac[k]);
            ad[k] = fmaf(x, wd[k], ad[k]);
        }
    }
#pragma unroll
    for (int k = 0; k < 20; ++k)
        for (int off = 1; off < 64; off <<= 1) {
            ac[k] += __shfl_xor(ac[k], off, 64);
            ad[k] += __shfl_xor(ad[k], off, 64);
        }
    for (int off = 1; off < 64; off <<= 1) aa += __shfl_xor(aa, off, 64);

    __shared__ float red[4][41];
    int wid = t >> 6, lane = t & 63;
    if (lane == 0) {
#pragma unroll
        for (int k = 0; k < 20; ++k) { red[wid][k] = ac[k]; red[wid][20+k] = ad[k]; }
        red[wid][40] = aa;
    }
    __syncthreads();
    __shared__ float lcs[20];
    if (t < 41) {
        float v = red[0][t] + red[1][t] + red[2][t] + red[3][t];
        if (t < 20)      lcs[t] = v + b8c[t];
        else if (t < 40) ld_out[r*K_ + (t-20)] = v + b8d[t-20];
        else             An[r] = v;
    }
    __syncthreads();
    if (t == 0) {   // row softmax over 20
        float mx = lcs[0];
#pragma unroll
        for (int k = 1; k < 20; ++k) mx = fmaxf(mx, lcs[k]);
        float s = 0.f, e[20];
#pragma unroll
        for (int k = 0; k < 20; ++k) { e[k] = expf(lcs[k] - mx); s += e[k]; }
        float inv = 1.f / s;
#pragma unroll
        for (int k = 0; k < 20; ++k) pc[r*K_ + k] = e[k] * inv;
    }
}

// ---- per-class column softmax, scores, column sum, argmin (stable) ----
__global__ void __launch_bounds__(256) k_pd(const float* __restrict__ ld,
        const float* __restrict__ pc, float* __restrict__ scores,
        float* __restrict__ out_sum, int* __restrict__ h_idx) {
    int k = blockIdx.x, t = threadIdx.x;
    __shared__ float sh[4];
    float m = -3.402823466e38f;
    for (int r = t; r < R_; r += 256) m = fmaxf(m, ld[r*K_ + k]);
    for (int off = 1; off < 64; off <<= 1) m = fmaxf(m, __shfl_xor(m, off, 64));
    if ((t & 63) == 0) sh[t >> 6] = m;
    __syncthreads();
    m = fmaxf(fmaxf(sh[0], sh[1]), fmaxf(sh[2], sh[3]));
    __syncthreads();
    float s = 0.f;
    for (int r = t; r < R_; r += 256) s += expf(ld[r*K_ + k] - m);
    for (int off = 1; off < 64; off <<= 1) s += __shfl_xor(s, off, 64);
    if ((t & 63) == 0) sh[t >> 6] = s;
    __syncthreads();
    s = sh[0] + sh[1] + sh[2] + sh[3];
    float inv = 1.f / s;

    float osum = 0.f, bv = 3.402823466e38f; int bi = 0x7fffffff;
    for (int r = t; r < R_; r += 256) {
        float p  = expf(ld[r*K_ + k] - m) * inv;
        float sc = pc[r*K_ + k] * p;
        scores[r*K_ + k] = sc;
        osum += sc;
        if (sc < bv || (sc == bv && r < bi)) { bv = sc; bi = r; }
    }
    for (int off = 1; off < 64; off <<= 1) osum += __shfl_xor(osum, off, 64);
    for (int off = 1; off < 64; off <<= 1) {
        float v2 = __shfl_xor(bv, off, 64);
        int   i2 = __shfl_xor(bi, off, 64);
        if (v2 < bv || (v2 == bv && i2 < bi)) { bv = v2; bi = i2; }
    }
    __shared__ float so[4], mv[4]; __shared__ int mi[4];
    if ((t & 63) == 0) { so[t >> 6] = osum; mv[t >> 6] = bv; mi[t >> 6] = bi; }
    __syncthreads();
    if (t == 0) {
        out_sum[k] = so[0] + so[1] + so[2] + so[3];
        float v = mv[0]; int i = mi[0];
        for (int w = 1; w < 4; ++w)
            if (mv[w] < v || (mv[w] == v && mi[w] < i)) { v = mv[w]; i = mi[w]; }
        h_idx[k] = i;
    }
}

// ---- D[r][k] = fc7[r] . fc7[h_k] ----
__global__ void __launch_bounds__(256) k_dmat(const float* __restrict__ fc7,
        const int* __restrict__ h_idx, float* __restrict__ D) {
    int r = blockIdx.x, t = threadIdx.x;
    const float* frow = fc7 + (size_t)r*HID;
    const float* hrow[20];
#pragma unroll
    for (int k = 0; k < 20; ++k) hrow[k] = fc7 + (size_t)h_idx[k]*HID;
    float acc[20] = {};
    for (int e = 0; e < 16; ++e) {
        int i = e*256 + t;
        float x = frow[i];
#pragma unroll
        for (int k = 0; k < 20; ++k) acc[k] = fmaf(x, hrow[k][i], acc[k]);
    }
#pragma unroll
    for (int k = 0; k < 20; ++k)
        for (int off = 1; off < 64; off <<= 1) acc[k] += __shfl_xor(acc[k], off, 64);
    __shared__ float red[4][20];
    int wid = t >> 6, lane = t & 63;
    if (lane == 0) {
#pragma unroll
        for (int k = 0; k < 20; ++k) red[wid][k] = acc[k];
    }
    __syncthreads();
    if (t < 20) D[r*K_ + t] = red[0][t] + red[1][t] + red[2][t] + red[3][t];
}

// ---- final: BCE + spatial regularizer ----
__global__ void __launch_bounds__(256) k_final(const float* __restrict__ out_sum,
        const int* __restrict__ h_idx, const float* __restrict__ label,
        const float* __restrict__ scores, const float* __restrict__ D,
        const float* __restrict__ An, const float* __restrict__ rois_sc,
        float* __restrict__ dout) {
    int t = threadIdx.x;
    __shared__ float bsh[20];
    if (t < 20) {
        float o = out_sum[t], lab = label[t];
        bsh[t] = lab * logf(o) + (1.f - lab) * logf(1.f - o);
    }
    __syncthreads();

    float rp = 0.f;
    for (int i = t; i < R_*K_; i += 256) {
        int r = i / 20, k = i - r*20;
        int h = h_idx[k];
        if (r == h) continue;
        float lab = label[k];
        if (lab == 0.f) continue;
        float s = scores[r*K_ + k];
        const float* rb = rois_sc + r*4;
        const float* hb = rois_sc + h*4;
        float b1x2 = rb[0] + rb[2], b1y2 = rb[1] + rb[3];
        float b2x2 = hb[0] + hb[2], b2y2 = hb[1] + hb[3];
        float iw = fmaxf(fminf(b1x2, b2x2) - fmaxf(rb[0], hb[0]) + 1.f, 0.f);
        float ih = fmaxf(fminf(b1y2, b2y2) - fmaxf(rb[1], hb[1]) + 1.f, 0.f);
        float inter = iw * ih;
        float a1 = (b1x2 - rb[0] + 1.f) * (b1y2 - rb[1] + 1.f);
        float a2 = (b2x2 - hb[0] + 1.f) * (b2y2 - hb[1] + 1.f);
        float iou = inter / (a1 + a2 - inter);
        float mm = (iou > 0.6f) ? 1.f : 0.f;
        float term = mm * (An[r] - 2.f * D[r*K_ + k]) + An[h];
        rp += lab * 0.5f * s * s * term;
    }
    for (int off = 1; off < 64; off <<= 1) rp += __shfl_xor(rp, off, 64);
    __shared__ float rsh[4];
    if ((t & 63) == 0) rsh[t >> 6] = rp;
    __syncthreads();
    if (t == 0) {
        float reg = (rsh[0] + rsh[1] + rsh[2] + rsh[3]) / (float)K_;
        float b = 0.f;
        for (int k = 0; k < 20; ++k) b += bsh[k];
        float bce = -b / (float)K_;
        dout[R_*K_]     = bce + reg;
        dout[R_*K_ + 1] = reg;
    }
}

extern "C" void kernel_launch(void* const* d_in, const int* in_sizes, int n_in,
                              void* d_out, int out_size, void* d_ws, size_t ws_size,
                              hipStream_t stream) {
    const float* fmap  = (const float*)d_in[0];
    const float* rois  = (const float*)d_in[1];
    const float* label = (const float*)d_in[2];
    const float* W6    = (const float*)d_in[3];
    const float* b6    = (const float*)d_in[4];
    const float* W7    = (const float*)d_in[5];
    const float* b7    = (const float*)d_in[6];
    const float* W8c   = (const float*)d_in[7];
    const float* b8c   = (const float*)d_in[8];
    const float* W8d   = (const float*)d_in[9];
    const float* b8d   = (const float*)d_in[10];
    char* ws = (char*)d_ws;
    float* out = (float*)d_out;

    float*  fmapt = (float*)(ws + O_FMT);
    float*  roisc = (float*)(ws + O_RSC);
    bf16_t* feat  = (bf16_t*)(ws + O_FEAT);
    bf16_t* fc6   = (bf16_t*)(ws + O_FC6);
    float*  fc7   = (float*)(ws + O_FC7);
    float*  pc    = (float*)(ws + O_PC);
    float*  ld    = (float*)(ws + O_LD);
    float*  An    = (float*)(ws + O_AN);
    float*  osum  = (float*)(ws + O_OS);
    int*    hidx  = (int*)(ws + O_HI);
    float*  Dm    = (float*)(ws + O_D);
    float*  part  = (float*)(ws + O_PART);

    int ksplit = (ws_size >= WS_K4) ? 4 : 1;

    k_transpose<<<dim3(H_*W_), dim3(256), 0, stream>>>(fmap, fmapt);
    k_roipool  <<<dim3(MP),    dim3(256), 0, stream>>>(fmapt, rois, feat, roisc);

    k_gemm  <<<dim3(HID/128, MP/128, ksplit), dim3(256), 0, stream>>>(feat, W6, part, FEAT, (FEAT/64)/ksplit);
    k_reduce<<<dim3((MP*HID)/1024), dim3(256), 0, stream>>>(part, b6, fc6, (float*)nullptr, ksplit);

    k_gemm  <<<dim3(HID/128, MP/128, ksplit), dim3(256), 0, stream>>>(fc6, W7, part, HID, (HID/64)/ksplit);
    k_reduce<<<dim3((MP*HID)/1024), dim3(256), 0, stream>>>(part, b7, (bf16_t*)nullptr, fc7, ksplit);

    k_heads<<<dim3(R_), dim3(256), 0, stream>>>(fc7, W8c, b8c, W8d, b8d, pc, ld, An);
    k_pd   <<<dim3(K_), dim3(256), 0, stream>>>(ld, pc, out, osum, hidx);
    k_dmat <<<dim3(R_), dim3(256), 0, stream>>>(fc7, hidx, Dm);
    k_final<<<dim3(1),  dim3(256), 0, stream>>>(osum, hidx, label, out, Dm, An, roisc, out);
}

// Round 2
// 176.606 us; speedup vs baseline: 1.3631x; 1.3631x over previous
//
#include <hip/hip_runtime.h>
#include <cstdint>
#include <cstddef>

#define DEV __device__ __forceinline__

typedef __bf16 bf16_t;
typedef __bf16 bf16x8 __attribute__((ext_vector_type(8)));
typedef float  f32x4  __attribute__((ext_vector_type(4)));
typedef unsigned int u32x4 __attribute__((ext_vector_type(4)));

DEV bf16_t f2bf(float x) { return (bf16_t)x; }   // RNE cast

// ---- problem sizes ----
constexpr int R_ = 500, C_ = 512, H_ = 38, W_ = 38, K_ = 20;
constexpr int HID = 4096, FEAT = 4608, MP = 512;  // MP = padded M
constexpr int HW = H_ * W_;                        // 1444

// ---- workspace layout ----
constexpr size_t alup(size_t x) { return (x + 255) & ~(size_t)255; }
constexpr size_t O_FMT  = 0;                                        // fmap transposed [1444][512] f32
constexpr size_t O_RSC  = alup(O_FMT  + (size_t)HW*C_*4);           // rois_sc [500][4] f32
constexpr size_t O_FEAT = alup(O_RSC  + (size_t)R_*4*4);            // feat bf16 [512][4608]
constexpr size_t O_FC6  = alup(O_FEAT + (size_t)MP*FEAT*2);         // fc6 bf16 [512][4096]
constexpr size_t O_FC7  = alup(O_FC6  + (size_t)MP*HID*2);          // fc7 f32 [512][4096]
constexpr size_t O_PC   = alup(O_FC7  + (size_t)MP*HID*4);          // pc [500][20] f32
constexpr size_t O_LD   = alup(O_PC   + (size_t)R_*K_*4);           // logits_d [500][20] f32
constexpr size_t O_AN   = alup(O_LD   + (size_t)R_*K_*4);           // ||fc7[r]||^2 [512] f32
constexpr size_t O_OS   = alup(O_AN   + (size_t)MP*4);              // out_sum [20]
constexpr size_t O_HI   = alup(O_OS   + (size_t)K_*4);              // h_idx [20] int
constexpr size_t O_D    = alup(O_HI   + (size_t)K_*4);              // D [500][20] f32
constexpr size_t O_W8T  = alup(O_D    + (size_t)R_*K_*4);           // W8T [40][4096] f32
constexpr size_t O_PART = alup(O_W8T  + (size_t)2*K_*HID*4);        // split-K partials
constexpr size_t WS_K4  = O_PART + (size_t)4*MP*HID*4;

// ---- fmap transpose: [C][HW] -> [HW][C], tiled through LDS (both sides coalesced) ----
__global__ void __launch_bounds__(256) k_transpose(const float* __restrict__ fmap,
                                                   float* __restrict__ fmapt) {
    __shared__ float tile[32][33];
    int p0 = blockIdx.x * 32, c0 = blockIdx.y * 32;
    int tx = threadIdx.x & 31, ty = threadIdx.x >> 5;     // ty in 0..7
#pragma unroll
    for (int i = 0; i < 4; ++i) {
        int c = c0 + ty + i*8, p = p0 + tx;
        tile[ty + i*8][tx] = (p < HW) ? fmap[(size_t)c*HW + p] : 0.f;
    }
    __syncthreads();
#pragma unroll
    for (int i = 0; i < 4; ++i) {
        int p = p0 + ty + i*8, c = c0 + tx;
        if (p < HW) fmapt[(size_t)p*C_ + c] = tile[tx][ty + i*8];
    }
}

// ---- W8c/W8d transpose: [4096][20] -> W8T[40][4096] ----
__global__ void __launch_bounds__(256) k_w8t(const float* __restrict__ W8c,
                                             const float* __restrict__ W8d,
                                             float* __restrict__ W8T) {
    int k = blockIdx.x;                                   // 0..39
    const float* src = (k < K_) ? W8c : W8d;
    int kk = (k < K_) ? k : k - K_;
    for (int i = threadIdx.x; i < HID; i += 256)
        W8T[(size_t)k*HID + i] = src[(size_t)i*K_ + kk];
}

// ---- ROI max pool, split over (roi, bin): feat[r, c*9 + bin] ----
__global__ void __launch_bounds__(256) k_roipool(const float* __restrict__ fmapt,
                                                 const float* __restrict__ rois,
                                                 bf16_t* __restrict__ feat,
                                                 float* __restrict__ rois_sc) {
    int r = blockIdx.x, bin = blockIdx.y, t = threadIdx.x;
    if (r >= R_) {   // zero the M-padding rows so the GEMM sees zeros
        feat[(size_t)r*FEAT + (size_t)t*9       + bin] = (bf16_t)0.f;
        feat[(size_t)r*FEAT + (size_t)(t+256)*9 + bin] = (bf16_t)0.f;
        return;
    }
    int x1 = (int)floorf(rois[r*4+0] * 0.0625f);
    int y1 = (int)floorf(rois[r*4+1] * 0.0625f);
    int x2 = (int)floorf(rois[r*4+2] * 0.0625f);
    int y2 = (int)floorf(rois[r*4+3] * 0.0625f);
    if (bin == 0 && t == 0) {
        rois_sc[r*4+0] = (float)x1; rois_sc[r*4+1] = (float)y1;
        rois_sc[r*4+2] = (float)x2; rois_sc[r*4+3] = (float)y2;
    }
    int Lx = x2 - x1, Ly = y2 - y1;
    int pr = bin / 3, px = bin - pr*3;
    int rs = y1 + (pr*Ly)/3, re = y1 + ((pr+1)*Ly + 2)/3;
    int cs = x1 + (px*Lx)/3, ce = x1 + ((px+1)*Lx + 2)/3;
    float m0 = -3.402823466e38f, m1 = -3.402823466e38f;
    for (int y = rs; y < re; ++y) {
        const float* rowp = fmapt + (size_t)(y*W_)*C_;
        for (int x = cs; x < ce; ++x) {
            const float* p = rowp + (size_t)x*C_;
            m0 = fmaxf(m0, p[t]);
            m1 = fmaxf(m1, p[t + 256]);
        }
    }
    feat[(size_t)r*FEAT + (size_t)t*9       + bin] = f2bf(m0);
    feat[(size_t)r*FEAT + (size_t)(t+256)*9 + bin] = f2bf(m1);
}

// ---- bf16 MFMA GEMM: part[s] += A[512xK](bf16) * B[Kx4096](f32, cast to bf16) ----
// BM=BN=128, BK=64, 4 waves (64x64 each), double-buffered LDS, split-K.
// XCD-aware remap: the 4 M-tiles (y) sharing a B panel are placed at stride-8
// slots (same XCD under round-robin dispatch) so B is fetched into one L2.
__global__ void __launch_bounds__(256, 2)
k_gemm(const bf16_t* __restrict__ A, const float* __restrict__ B,
       float* __restrict__ part, int KDIM, int nts) {
    __shared__ bf16_t Al[2][128][72];   // 144B row stride: uniform bank spread for b128
    __shared__ bf16_t Bl[2][128][72];   // stored transposed: [n][k]
    const int t = threadIdx.x;
    const int lane = t & 63, wid = t >> 6;
    const int wr = wid >> 1, wc = wid & 1;

    // flat block id -> (bx, by, bz) with y-group co-located per XCD
    const int flat = blockIdx.x + 32 * (blockIdx.y + 4 * blockIdx.z);  // 0..511
    const int xcd = flat & 7, slot = flat >> 3;
    const int grp = xcd * 16 + (slot >> 2);            // 0..127
    const int by = slot & 3;
    const int bx = grp & 31, bz = grp >> 5;

    const int brow = by * 128, bcol = bx * 128;
    const int kt0 = bz * nts;

    f32x4 acc[4][4] = {};
    u32x4 areg[4];
    float breg[4][8];

    auto load_tile = [&](int kt) {
        const int k0 = kt * 64;
#pragma unroll
        for (int i = 0; i < 4; ++i) {          // A: 128 rows x 64 k, 16B per slot
            int slot2 = t + i*256;
            int row = slot2 >> 3, kg = slot2 & 7;
            areg[i] = *reinterpret_cast<const u32x4*>(A + (size_t)(brow + row)*KDIM + k0 + kg*8);
        }
#pragma unroll
        for (int i = 0; i < 4; ++i) {          // B: columnar gather (8 consecutive k per n)
            int slot2 = t + i*256;
            int n = slot2 & 127, kg = slot2 >> 7;
            const float* src = B + (size_t)(k0 + kg*8)*HID + bcol + n;
#pragma unroll
            for (int j = 0; j < 8; ++j) breg[i][j] = src[(size_t)j*HID];
        }
    };
    auto write_tile = [&](int buf) {
#pragma unroll
        for (int i = 0; i < 4; ++i) {
            int slot2 = t + i*256;
            int row = slot2 >> 3, kg = slot2 & 7;
            *reinterpret_cast<u32x4*>(&Al[buf][row][kg*8]) = areg[i];
        }
#pragma unroll
        for (int i = 0; i < 4; ++i) {
            int slot2 = t + i*256;
            int n = slot2 & 127, kg = slot2 >> 7;
            bf16x8 v;
#pragma unroll
            for (int j = 0; j < 8; ++j) v[j] = f2bf(breg[i][j]);
            *reinterpret_cast<bf16x8*>(&Bl[buf][n][kg*8]) = v;
        }
    };

    load_tile(kt0);
    write_tile(0);
    __syncthreads();

    for (int it = 0; it < nts; ++it) {
        const int cur = it & 1;
        if (it + 1 < nts) load_tile(kt0 + it + 1);   // overlap global loads with MFMA
#pragma unroll
        for (int kk = 0; kk < 2; ++kk) {
            bf16x8 af[4], bfr[4];
#pragma unroll
            for (int m = 0; m < 4; ++m)
                af[m] = *reinterpret_cast<const bf16x8*>(
                    &Al[cur][wr*64 + m*16 + (lane & 15)][kk*32 + (lane >> 4)*8]);
#pragma unroll
            for (int n = 0; n < 4; ++n)
                bfr[n] = *reinterpret_cast<const bf16x8*>(
                    &Bl[cur][wc*64 + n*16 + (lane & 15)][kk*32 + (lane >> 4)*8]);
#pragma unroll
            for (int m = 0; m < 4; ++m)
#pragma unroll
                for (int n = 0; n < 4; ++n)
                    acc[m][n] = __builtin_amdgcn_mfma_f32_16x16x32_bf16(af[m], bfr[n], acc[m][n], 0, 0, 0);
        }
        if (it + 1 < nts) { write_tile(cur ^ 1); __syncthreads(); }
    }

    float* dst = part + (size_t)bz * MP * HID;
#pragma unroll
    for (int m = 0; m < 4; ++m) {
        int row0 = brow + wr*64 + m*16 + ((lane >> 4) << 2);
#pragma unroll
        for (int n = 0; n < 4; ++n) {
            int col = bcol + wc*64 + n*16 + (lane & 15);
#pragma unroll
            for (int j = 0; j < 4; ++j)
                dst[(size_t)(row0 + j)*HID + col] = acc[m][n][j];
        }
    }
}

// ---- split-K reduce + bias; writes bf16 (fc6) or f32 (fc7) ----
__global__ void __launch_bounds__(256) k_reduce(const float* __restrict__ part,
                                                const float* __restrict__ bias,
                                                bf16_t* __restrict__ ob, float* __restrict__ of,
                                                int ksplit) {
    size_t idx = ((size_t)blockIdx.x*256 + threadIdx.x) * 4;
    f32x4 s = *reinterpret_cast<const f32x4*>(part + idx);
    for (int ss = 1; ss < ksplit; ++ss)
        s += *reinterpret_cast<const f32x4*>(part + (size_t)ss*MP*HID + idx);
    int col = (int)(idx & (HID - 1));
    s += *reinterpret_cast<const f32x4*>(bias + col);
    if (ob) {
#pragma unroll
        for (int j = 0; j < 4; ++j) ob[idx + j] = f2bf(s[j]);
    } else {
        *reinterpret_cast<f32x4*>(of + idx) = s;
    }
}

// ---- heads: logits_c (+softmax -> pc), logits_d (raw), ||fc7[r]||^2 ----
__global__ void __launch_bounds__(256) k_heads(const float* __restrict__ fc7,
        const float* __restrict__ W8T,
        const float* __restrict__ b8c, const float* __restrict__ b8d,
        float* __restrict__ pc, float* __restrict__ ld_out, float* __restrict__ An) {
    int r = blockIdx.x, t = threadIdx.x;
    float ac[20] = {}, ad[20] = {}, aa = 0.f;
    const float* frow = fc7 + (size_t)r*HID;
    for (int e = 0; e < 16; ++e) {
        int i = e*256 + t;
        float x = frow[i];
        aa = fmaf(x, x, aa);
#pragma unroll
        for (int k = 0; k < 20; ++k) {
            ac[k] = fmaf(x, W8T[(size_t)k*HID + i], ac[k]);
            ad[k] = fmaf(x, W8T[(size_t)(K_ + k)*HID + i], ad[k]);
        }
    }
#pragma unroll
    for (int k = 0; k < 20; ++k)
        for (int off = 1; off < 64; off <<= 1) {
            ac[k] += __shfl_xor(ac[k], off, 64);
            ad[k] += __shfl_xor(ad[k], off, 64);
        }
    for (int off = 1; off < 64; off <<= 1) aa += __shfl_xor(aa, off, 64);

    __shared__ float red[4][41];
    int wid = t >> 6, lane = t & 63;
    if (lane == 0) {
#pragma unroll
        for (int k = 0; k < 20; ++k) { red[wid][k] = ac[k]; red[wid][20+k] = ad[k]; }
        red[wid][40] = aa;
    }
    __syncthreads();
    __shared__ float lcs[20];
    if (t < 41) {
        float v = red[0][t] + red[1][t] + red[2][t] + red[3][t];
        if (t < 20)      lcs[t] = v + b8c[t];
        else if (t < 40) ld_out[r*K_ + (t-20)] = v + b8d[t-20];
        else             An[r] = v;
    }
    __syncthreads();
    if (t == 0) {   // row softmax over 20
        float mx = lcs[0];
#pragma unroll
        for (int k = 1; k < 20; ++k) mx = fmaxf(mx, lcs[k]);
        float s = 0.f, e[20];
#pragma unroll
        for (int k = 0; k < 20; ++k) { e[k] = expf(lcs[k] - mx); s += e[k]; }
        float inv = 1.f / s;
#pragma unroll
        for (int k = 0; k < 20; ++k) pc[r*K_ + k] = e[k] * inv;
    }
}

// ---- per-class column softmax, scores, column sum, argmin (stable) ----
__global__ void __launch_bounds__(256) k_pd(const float* __restrict__ ld,
        const float* __restrict__ pc, float* __restrict__ scores,
        float* __restrict__ out_sum, int* __restrict__ h_idx) {
    int k = blockIdx.x, t = threadIdx.x;
    __shared__ float sh[4];
    float m = -3.402823466e38f;
    for (int r = t; r < R_; r += 256) m = fmaxf(m, ld[r*K_ + k]);
    for (int off = 1; off < 64; off <<= 1) m = fmaxf(m, __shfl_xor(m, off, 64));
    if ((t & 63) == 0) sh[t >> 6] = m;
    __syncthreads();
    m = fmaxf(fmaxf(sh[0], sh[1]), fmaxf(sh[2], sh[3]));
    __syncthreads();
    float s = 0.f;
    for (int r = t; r < R_; r += 256) s += expf(ld[r*K_ + k] - m);
    for (int off = 1; off < 64; off <<= 1) s += __shfl_xor(s, off, 64);
    if ((t & 63) == 0) sh[t >> 6] = s;
    __syncthreads();
    s = sh[0] + sh[1] + sh[2] + sh[3];
    float inv = 1.f / s;

    float osum = 0.f, bv = 3.402823466e38f; int bi = 0x7fffffff;
    for (int r = t; r < R_; r += 256) {
        float p  = expf(ld[r*K_ + k] - m) * inv;
        float sc = pc[r*K_ + k] * p;
        scores[r*K_ + k] = sc;
        osum += sc;
        if (sc < bv || (sc == bv && r < bi)) { bv = sc; bi = r; }
    }
    for (int off = 1; off < 64; off <<= 1) osum += __shfl_xor(osum, off, 64);
    for (int off = 1; off < 64; off <<= 1) {
        float v2 = __shfl_xor(bv, off, 64);
        int   i2 = __shfl_xor(bi, off, 64);
        if (v2 < bv || (v2 == bv && i2 < bi)) { bv = v2; bi = i2; }
    }
    __shared__ float so[4], mv[4]; __shared__ int mi[4];
    if ((t & 63) == 0) { so[t >> 6] = osum; mv[t >> 6] = bv; mi[t >> 6] = bi; }
    __syncthreads();
    if (t == 0) {
        out_sum[k] = so[0] + so[1] + so[2] + so[3];
        float v = mv[0]; int i = mi[0];
        for (int w = 1; w < 4; ++w)
            if (mv[w] < v || (mv[w] == v && mi[w] < i)) { v = mv[w]; i = mi[w]; }
        h_idx[k] = i;
    }
}

// ---- D[r][k] = fc7[r] . fc7[h_k] ----
__global__ void __launch_bounds__(256) k_dmat(const float* __restrict__ fc7,
        const int* __restrict__ h_idx, float* __restrict__ D) {
    int r = blockIdx.x, t = threadIdx.x;
    const float* frow = fc7 + (size_t)r*HID;
    const float* hrow[20];
#pragma unroll
    for (int k = 0; k < 20; ++k) hrow[k] = fc7 + (size_t)h_idx[k]*HID;
    float acc[20] = {};
    for (int e = 0; e < 16; ++e) {
        int i = e*256 + t;
        float x = frow[i];
#pragma unroll
        for (int k = 0; k < 20; ++k) acc[k] = fmaf(x, hrow[k][i], acc[k]);
    }
#pragma unroll
    for (int k = 0; k < 20; ++k)
        for (int off = 1; off < 64; off <<= 1) acc[k] += __shfl_xor(acc[k], off, 64);
    __shared__ float red[4][20];
    int wid = t >> 6, lane = t & 63;
    if (lane == 0) {
#pragma unroll
        for (int k = 0; k < 20; ++k) red[wid][k] = acc[k];
    }
    __syncthreads();
    if (t < 20) D[r*K_ + t] = red[0][t] + red[1][t] + red[2][t] + red[3][t];
}

// ---- final: BCE + spatial regularizer ----
__global__ void __launch_bounds__(256) k_final(const float* __restrict__ out_sum,
        const int* __restrict__ h_idx, const float* __restrict__ label,
        const float* __restrict__ scores, const float* __restrict__ D,
        const float* __restrict__ An, const float* __restrict__ rois_sc,
        float* __restrict__ dout) {
    int t = threadIdx.x;
    __shared__ float bsh[20];
    if (t < 20) {
        float o = out_sum[t], lab = label[t];
        bsh[t] = lab * logf(o) + (1.f - lab) * logf(1.f - o);
    }
    __syncthreads();

    float rp = 0.f;
    for (int i = t; i < R_*K_; i += 256) {
        int r = i / 20, k = i - r*20;
        int h = h_idx[k];
        if (r == h) continue;
        float lab = label[k];
        if (lab == 0.f) continue;
        float s = scores[r*K_ + k];
        const float* rb = rois_sc + r*4;
        const float* hb = rois_sc + h*4;
        float b1x2 = rb[0] + rb[2], b1y2 = rb[1] + rb[3];
        float b2x2 = hb[0] + hb[2], b2y2 = hb[1] + hb[3];
        float iw = fmaxf(fminf(b1x2, b2x2) - fmaxf(rb[0], hb[0]) + 1.f, 0.f);
        float ih = fmaxf(fminf(b1y2, b2y2) - fmaxf(rb[1], hb[1]) + 1.f, 0.f);
        float inter = iw * ih;
        float a1 = (b1x2 - rb[0] + 1.f) * (b1y2 - rb[1] + 1.f);
        float a2 = (b2x2 - hb[0] + 1.f) * (b2y2 - hb[1] + 1.f);
        float iou = inter / (a1 + a2 - inter);
        float mm = (iou > 0.6f) ? 1.f : 0.f;
        float term = mm * (An[r] - 2.f * D[r*K_ + k]) + An[h];
        rp += lab * 0.5f * s * s * term;
    }
    for (int off = 1; off < 64; off <<= 1) rp += __shfl_xor(rp, off, 64);
    __shared__ float rsh[4];
    if ((t & 63) == 0) rsh[t >> 6] = rp;
    __syncthreads();
    if (t == 0) {
        float reg = (rsh[0] + rsh[1] + rsh[2] + rsh[3]) / (float)K_;
        float b = 0.f;
        for (int k = 0; k < 20; ++k) b += bsh[k];
        float bce = -b / (float)K_;
        dout[R_*K_]     = bce + reg;
        dout[R_*K_ + 1] = reg;
    }
}

extern "C" void kernel_launch(void* const* d_in, const int* in_sizes, int n_in,
                              void* d_out, int out_size, void* d_ws, size_t ws_size,
                              hipStream_t stream) {
    const float* fmap  = (const float*)d_in[0];
    const float* rois  = (const float*)d_in[1];
    const float* label = (const float*)d_in[2];
    const float* W6    = (const float*)d_in[3];
    const float* b6    = (const float*)d_in[4];
    const float* W7    = (const float*)d_in[5];
    const float* b7    = (const float*)d_in[6];
    const float* W8c   = (const float*)d_in[7];
    const float* b8c   = (const float*)d_in[8];
    const float* W8d   = (const float*)d_in[9];
    const float* b8d   = (const float*)d_in[10];
    char* ws = (char*)d_ws;
    float* out = (float*)d_out;

    float*  fmapt = (float*)(ws + O_FMT);
    float*  roisc = (float*)(ws + O_RSC);
    bf16_t* feat  = (bf16_t*)(ws + O_FEAT);
    bf16_t* fc6   = (bf16_t*)(ws + O_FC6);
    float*  fc7   = (float*)(ws + O_FC7);
    float*  pc    = (float*)(ws + O_PC);
    float*  ld    = (float*)(ws + O_LD);
    float*  An    = (float*)(ws + O_AN);
    float*  osum  = (float*)(ws + O_OS);
    int*    hidx  = (int*)(ws + O_HI);
    float*  Dm    = (float*)(ws + O_D);
    float*  w8t   = (float*)(ws + O_W8T);
    float*  part  = (float*)(ws + O_PART);

    int ksplit = (ws_size >= WS_K4) ? 4 : 1;

    k_transpose<<<dim3((HW + 31)/32, C_/32), dim3(256), 0, stream>>>(fmap, fmapt);
    k_w8t      <<<dim3(2*K_),   dim3(256), 0, stream>>>(W8c, W8d, w8t);
    k_roipool  <<<dim3(MP, 9),  dim3(256), 0, stream>>>(fmapt, rois, feat, roisc);

    k_gemm  <<<dim3(HID/128, MP/128, ksplit), dim3(256), 0, stream>>>(feat, W6, part, FEAT, (FEAT/64)/ksplit);
    k_reduce<<<dim3((MP*HID)/1024), dim3(256), 0, stream>>>(part, b6, fc6, (float*)nullptr, ksplit);

    k_gemm  <<<dim3(HID/128, MP/128, ksplit), dim3(256), 0, stream>>>(fc6, W7, part, HID, (HID/64)/ksplit);
    k_reduce<<<dim3((MP*HID)/1024), dim3(256), 0, stream>>>(part, b7, (bf16_t*)nullptr, fc7, ksplit);

    k_heads<<<dim3(R_), dim3(256), 0, stream>>>(fc7, w8t, b8c, b8d, pc, ld, An);
    k_pd   <<<dim3(K_), dim3(256), 0, stream>>>(ld, pc, out, osum, hidx);
    k_dmat <<<dim3(R_), dim3(256), 0, stream>>>(fc7, hidx, Dm);
    k_final<<<dim3(1),  dim3(256), 0, stream>>>(osum, hidx, label, out, Dm, An, roisc, out);
}